// Round 12
// baseline (184.548 us; speedup 1.0000x reference)
//
#include <hip/hip_runtime.h>

#define B_ 64
#define A_ 1024
#define C_ 64
#define D_ 512
#define INV_SD 0.044194173824159216f

typedef __bf16 bf16_t;
typedef __bf16 bf16x8 __attribute__((ext_vector_type(8)));
typedef __bf16 bf16x2 __attribute__((ext_vector_type(2)));
typedef float f32x4 __attribute__((ext_vector_type(4)));

static __device__ __forceinline__ bf16_t f2b(float x) { return (bf16_t)x; }
static __device__ __forceinline__ float b2f(bf16_t x) { return (float)x; }

// async global->LDS, 16B per lane; LDS dest = wave-uniform base + lane*16 (linear)
static __device__ __forceinline__ void gl_lds16(const void* g, void* l) {
  __builtin_amdgcn_global_load_lds(
      (const __attribute__((address_space(1))) unsigned int*)g,
      (__attribute__((address_space(3))) unsigned int*)l, 16, 0, 0);
}

// ---- merged prep: blocks [0, B*C) do hl0 (LN11+avg+LN12 -> hln bf16);
//      blocks [B*C, B*C+384) do weight transpose/convert (6 slots) ----
__global__ __launch_bounds__(256) void k_prep(const float* __restrict__ att,
                                              const float* __restrict__ lw1,
                                              const float* __restrict__ lb1,
                                              const float* __restrict__ lw2,
                                              const float* __restrict__ lb2,
                                              bf16_t* __restrict__ hlnb,
                                              const float* __restrict__ W0,
                                              const float* __restrict__ W1,
                                              const float* __restrict__ W2,
                                              const float* __restrict__ W3,
                                              const float* __restrict__ W4,
                                              bf16_t* __restrict__ WtBase) {
  __shared__ float shm[64 * 65];  // 16.6 KB, aliased by both paths
  __shared__ float reds[8];
  int bid = blockIdx.x;
  int t = threadIdx.x;
  if (bid < B_ * C_) {
    int b = bid >> 6, c = bid & 63;
    int w = t >> 6, lane = t & 63;
    float (*part)[512] = (float(*)[512])shm;
    float vv[4][8];
#pragma unroll
    for (int i = 0; i < 4; ++i) {  // hoisted loads: 4 rows in flight
      int jj = w * 4 + i;
      const float* xr = att + ((size_t)b * A_ + jj * 64 + c) * D_ + lane * 8;
      float4 v1 = *(const float4*)xr;
      float4 v2 = *(const float4*)(xr + 4);
      vv[i][0] = v1.x; vv[i][1] = v1.y; vv[i][2] = v1.z; vv[i][3] = v1.w;
      vv[i][4] = v2.x; vv[i][5] = v2.y; vv[i][6] = v2.z; vv[i][7] = v2.w;
    }
    float ps[8] = {0.f, 0.f, 0.f, 0.f, 0.f, 0.f, 0.f, 0.f};
#pragma unroll
    for (int i = 0; i < 4; ++i) {
      float s = 0.f, q = 0.f;
#pragma unroll
      for (int u = 0; u < 8; ++u) { s += vv[i][u]; q += vv[i][u] * vv[i][u]; }
#pragma unroll
      for (int o = 32; o; o >>= 1) { s += __shfl_xor(s, o); q += __shfl_xor(q, o); }
      float mu = s * (1.0f / D_);
      float rs = rsqrtf(q * (1.0f / D_) - mu * mu + 1e-5f);
#pragma unroll
      for (int u = 0; u < 8; ++u) ps[u] += (vv[i][u] - mu) * rs;
    }
#pragma unroll
    for (int u = 0; u < 8; ++u) part[w][lane * 8 + u] = ps[u];
    __syncthreads();
    int d = 2 * t;
    float hx = ((part[0][d] + part[1][d]) + (part[2][d] + part[3][d])) * (1.f / 16.f) * lw1[d] + lb1[d];
    float hy = ((part[0][d + 1] + part[1][d + 1]) + (part[2][d + 1] + part[3][d + 1])) * (1.f / 16.f) * lw1[d + 1] + lb1[d + 1];
    float s = hx + hy, q = hx * hx + hy * hy;
#pragma unroll
    for (int o = 32; o; o >>= 1) { s += __shfl_xor(s, o); q += __shfl_xor(q, o); }
    int lane2 = t & 63, w2 = t >> 6;
    if (lane2 == 0) { reds[w2] = s; reds[4 + w2] = q; }
    __syncthreads();
    float S = (reds[0] + reds[1]) + (reds[2] + reds[3]);
    float Q = (reds[4] + reds[5]) + (reds[6] + reds[7]);
    float mu = S * (1.0f / D_);
    float rs = rsqrtf(Q * (1.0f / D_) - mu * mu + 1e-5f);
    bf16x2 ob;
    ob.x = f2b((hx - mu) * rs * lw2[d] + lb2[d]);
    ob.y = f2b((hy - mu) * rs * lw2[d + 1] + lb2[d + 1]);
    *(bf16x2*)(hlnb + (size_t)bid * D_ + d) = ob;
  } else {
    int idx = bid - B_ * C_;
    int z = idx >> 6;  // 0..5
    int rem = idx & 63;
    int k0 = (rem & 7) * 64, n0 = (rem >> 3) * 64;
    const float* Ws[5] = {W0, W1, W2, W3, W4};
    int r0 = t >> 6;
    int c = t & 63;
    if (z == 5) {  // raw bf16 convert of W2_a2h
      const float* W = Ws[2];
      bf16_t* Wt = WtBase + (size_t)5 * 512 * 512;
#pragma unroll 4
      for (int i = 0; i < 16; ++i) {
        int r = r0 * 16 + i;
        Wt[(size_t)(k0 + r) * 512 + n0 + c] = f2b(W[(size_t)(k0 + r) * 512 + n0 + c]);
      }
      return;
    }
    const float* W = Ws[z];
    bf16_t* Wt = WtBase + (size_t)z * 512 * 512;
    float (*tile)[65] = (float(*)[65])shm;
#pragma unroll 4
    for (int i = 0; i < 16; ++i) {
      int r = r0 * 16 + i;
      tile[r][c] = W[(size_t)(k0 + r) * 512 + n0 + c];
    }
    __syncthreads();
#pragma unroll 4
    for (int i = 0; i < 16; ++i) {
      int r = r0 * 16 + i;
      Wt[(size_t)(n0 + r) * 512 + k0 + c] = f2b(tile[c][r]);
    }
  }
}

// ---- merged: LN rows of one batch (bf16 in) -> row-major bf16 + transposed bf16 ----
__global__ __launch_bounds__(256) void k_ln_tr(const bf16_t* __restrict__ x,
                                               const float* __restrict__ lw,
                                               const float* __restrict__ lb,
                                               bf16_t* __restrict__ y,
                                               bf16_t* __restrict__ yt) {
  __shared__ bf16_t lnS[64][528];
  int b = blockIdx.x;
  int t = threadIdx.x;
  int wv = t >> 6, lane = t & 63;
  int d0 = lane * 8;
  float4 w1 = *(const float4*)(lw + d0);
  float4 w2 = *(const float4*)(lw + d0 + 4);
  float4 b1 = *(const float4*)(lb + d0);
  float4 b2 = *(const float4*)(lb + d0 + 4);
  float lwv[8] = {w1.x, w1.y, w1.z, w1.w, w2.x, w2.y, w2.z, w2.w};
  float lbv[8] = {b1.x, b1.y, b1.z, b1.w, b2.x, b2.y, b2.z, b2.w};
  const bf16_t* xb = x + (size_t)b * C_ * D_;
  bf16_t* yb = y + (size_t)b * C_ * D_;
#pragma unroll 4
  for (int i = 0; i < 16; ++i) {
    int r = wv * 16 + i;
    bf16x8 xv = *(const bf16x8*)(xb + (size_t)r * D_ + d0);
    float v[8], s = 0.f, q = 0.f;
#pragma unroll
    for (int u = 0; u < 8; ++u) { v[u] = b2f(xv[u]); s += v[u]; q += v[u] * v[u]; }
#pragma unroll
    for (int o = 32; o; o >>= 1) { s += __shfl_xor(s, o); q += __shfl_xor(q, o); }
    float mu = s * (1.0f / D_);
    float rs = rsqrtf(q * (1.0f / D_) - mu * mu + 1e-5f);
    bf16x8 ob;
#pragma unroll
    for (int u = 0; u < 8; ++u) ob[u] = f2b((v[u] - mu) * rs * lwv[u] + lbv[u]);
    *(bf16x8*)(yb + (size_t)r * D_ + d0) = ob;
    *(bf16x8*)(&lnS[r][d0]) = ob;
  }
  __syncthreads();
  bf16_t* tb = yt + (size_t)b * D_ * C_;
#pragma unroll
  for (int pass = 0; pass < 16; ++pass) {
    int d = pass * 32 + (t >> 3);
    int c0 = (t & 7) * 8;
    unsigned short tmp[8];
#pragma unroll
    for (int u = 0; u < 8; ++u) tmp[u] = *(const unsigned short*)&lnS[c0 + u][d];
    *(uint4*)(tb + (size_t)d * 64 + c0) = *(const uint4*)tmp;
  }
}

// ---- MFMA GEMM, 32x64 tiles, BK=64, dbuf LDS (24KB -> 4 blocks/CU), dual-matrix
//      merge + optional appended transpose blocks ----
template <bool BIAS>
__global__ __launch_bounds__(256, 4) void k_gemm32(const bf16_t* __restrict__ A0,
                                                   const bf16_t* __restrict__ W0,
                                                   bf16_t* __restrict__ C0,
                                                   const bf16_t* __restrict__ A1,
                                                   const bf16_t* __restrict__ W1,
                                                   bf16_t* __restrict__ C1,
                                                   const bf16_t* __restrict__ Rb,
                                                   int tiles_per, int ntiles,
                                                   const bf16_t* __restrict__ trS,
                                                   bf16_t* __restrict__ trD) {
  constexpr int ABYTES = 32 * 128;      // 4 KB
  constexpr int BBYTES = 64 * 128;      // 8 KB
  constexpr int BUF = ABYTES + BBYTES;  // 12 KB
  __shared__ char smem[2 * BUF];        // 24 KB; epilogue Cs + tr path alias

  int t = threadIdx.x;
  int bid = blockIdx.x;

  if (bid >= ntiles) {  // appended transpose block
    int idx = bid - ntiles;
    int n0 = idx & 7, b = idx >> 3;
    unsigned short(*sm)[72] = (unsigned short(*)[72])smem;  // 9.2 KB <= 24 KB
    const bf16_t* sb = trS + (size_t)b * C_ * D_;
    bf16_t* db = trD + (size_t)b * D_ * C_;
#pragma unroll
    for (int rep = 0; rep < 2; ++rep) {
      int f = t + rep * 256;
      int r = f >> 3, c8 = f & 7;
      uint4 v = *(const uint4*)(sb + (size_t)r * D_ + n0 * 64 + c8 * 8);
      unsigned int* p = (unsigned int*)&sm[r][c8 * 8];
      p[0] = v.x; p[1] = v.y; p[2] = v.z; p[3] = v.w;
    }
    __syncthreads();
#pragma unroll
    for (int rep = 0; rep < 2; ++rep) {
      int f = t + rep * 256;
      int nr = f >> 3, c8 = f & 7;
      unsigned short tmp[8];
#pragma unroll
      for (int u = 0; u < 8; ++u) tmp[u] = sm[c8 * 8 + u][nr];
      *(uint4*)(db + (size_t)(n0 * 64 + nr) * 64 + c8 * 8) = *(const uint4*)tmp;
    }
    return;
  }

  int lane = t & 63, wave = t >> 6;
  int wr = wave & 1, wc = wave >> 1;  // wave tile: rows wr*16, cols wc*32
  int lhi = lane >> 4, llo = lane & 15;

  int tile = (bid & 7) * (ntiles >> 3) + (bid >> 3);
  int sel = (tile >= tiles_per) ? 1 : 0;
  int tidx = tile - sel * tiles_per;
  int bm = tidx >> 3, bn = tidx & 7;

  const bf16_t* Ab = (sel ? A1 : A0) + (size_t)bm * 32 * 512;
  const bf16_t* Wb = (sel ? W1 : W0) + (size_t)bn * 64 * 512;
  bf16_t* Cmat = sel ? C1 : C0;

  int l3 = lane >> 3;
  int srcOff = ((lane & 7) ^ l3) * 8;  // pre-swizzled source (rule 21)

  auto stage = [&](int k0, int bi) {
    char* As = smem + bi * BUF;
    char* Bs = As + ABYTES;
    int r0 = wave * 8;  // A: 32 rows = 4 wave-ops (1 per wave)
    gl_lds16(Ab + (size_t)(r0 + l3) * 512 + k0 + srcOff, As + r0 * 128);
#pragma unroll
    for (int i = 0; i < 2; ++i) {  // B: 64 rows = 8 wave-ops (2 per wave)
      int rb0 = wave * 16 + i * 8;
      gl_lds16(Wb + (size_t)(rb0 + l3) * 512 + k0 + srcOff, Bs + rb0 * 128);
    }
  };

  f32x4 acc[2] = {};
  stage(0, 0);
  __syncthreads();

  for (int it = 0; it < 8; ++it) {
    int cur = it & 1;
    if (it < 7) stage((it + 1) * 64, cur ^ 1);  // issue BEFORE compute
    const char* As = smem + cur * BUF;
    const char* Bs = As + ABYTES;
#pragma unroll
    for (int kk = 0; kk < 2; ++kk) {
      int bofs = kk * 64 + lhi * 16;
      int row = wr * 16 + llo;
      bf16x8 af = *(const bf16x8*)(As + row * 128 + (bofs ^ ((row & 7) << 4)));
#pragma unroll
      for (int tc = 0; tc < 2; ++tc) {
        int col = wc * 32 + tc * 16 + llo;
        bf16x8 bfr = *(const bf16x8*)(Bs + col * 128 + (bofs ^ ((col & 7) << 4)));
        acc[tc] = __builtin_amdgcn_mfma_f32_16x16x32_bf16(af, bfr, acc[tc], 0, 0, 0);
      }
    }
    __syncthreads();
  }

  bf16_t(*Cs)[80] = (bf16_t(*)[80])smem;  // 32 x 80 bf16 = 5 KB
  {
    int row = wr * 16 + lhi * 4;
#pragma unroll
    for (int r = 0; r < 4; ++r)
#pragma unroll
      for (int tc = 0; tc < 2; ++tc) {
        float v = acc[tc][r];
        if constexpr (BIAS)
          v += b2f(Rb[(size_t)(bm * 32 + row + r) * 512 + bn * 64 + wc * 32 + tc * 16 + llo]);
        Cs[row + r][wc * 32 + tc * 16 + llo] = f2b(v);
      }
  }
  __syncthreads();
  {
    int rw = t >> 3, c8 = t & 7;  // 32 rows x 8 chunks = 256 threads
    uint4 v = *(const uint4*)(&Cs[rw][c8 * 8]);
    *(uint4*)(Cmat + (size_t)(bm * 32 + rw) * 512 + bn * 64 + c8 * 8) = v;
  }
}

// ---- fused h2h: gram(MFMA) + softmax + PV(MFMA) + epilogue LN ----
// MODE 0: write hl1f (f32), hl1b (bf16), lnout=LN(hl1) bf16.  MODE 1: lnout only.
template <int MODE>
__global__ __launch_bounds__(256) void k_h2h(const bf16_t* __restrict__ hide,
                                             const bf16_t* __restrict__ hlnT,
                                             const float* __restrict__ lnw,
                                             const float* __restrict__ lnbv,
                                             float* __restrict__ hl1f,
                                             bf16_t* __restrict__ hl1b,
                                             bf16_t* __restrict__ lnout) {
  __shared__ bf16_t hS[8 * 64 * 64];  // 64KB; reused as f32 sf[16][516] in epilogue
  __shared__ float sS[16][68];
  __shared__ bf16_t wS[16 * 64];
  __shared__ float mur[16], rsr[16];

  int q = blockIdx.x;
  int b = blockIdx.y;
  int t = threadIdx.x;
  int lane = t & 63, wave = t >> 6;
  int lhi = lane >> 4, llo = lane & 15;

  const bf16_t* Hb = hide + (size_t)b * C_ * D_;
#pragma unroll
  for (int rep = 0; rep < 16; ++rep) {
    int f = t + rep * 256;
    int row = f >> 6, c16 = f & 63;
    int kc = c16 >> 3, ci = c16 & 7;
    uint4 v = *(const uint4*)(Hb + (size_t)row * 512 + c16 * 8);
    *(uint4*)((char*)hS + kc * 8192 + row * 128 + ((ci * 16) ^ ((row & 7) << 4))) = v;
  }
  __syncthreads();

  {
    f32x4 acc = {};
#pragma unroll
    for (int ks = 0; ks < 16; ++ks) {
      int kc = ks >> 1;
      int bofs = (ks & 1) * 64 + lhi * 16;
      int ra = q * 16 + llo;
      int rb = wave * 16 + llo;
      bf16x8 af = *(const bf16x8*)((const char*)hS + kc * 8192 + ra * 128 + (bofs ^ ((ra & 7) << 4)));
      bf16x8 bf = *(const bf16x8*)((const char*)hS + kc * 8192 + rb * 128 + (bofs ^ ((rb & 7) << 4)));
      acc = __builtin_amdgcn_mfma_f32_16x16x32_bf16(af, bf, acc, 0, 0, 0);
    }
#pragma unroll
    for (int r = 0; r < 4; ++r) sS[lhi * 4 + r][wave * 16 + llo] = acc[r] * INV_SD;
  }
  __syncthreads();

  if (t < 128) {
    int row = t >> 3, sg = t & 7;
    float v[8];
#pragma unroll
    for (int u = 0; u < 8; ++u) v[u] = sS[row][sg * 8 + u];
    float m = v[0];
#pragma unroll
    for (int u = 1; u < 8; ++u) m = fmaxf(m, v[u]);
#pragma unroll
    for (int o = 4; o; o >>= 1) m = fmaxf(m, __shfl_xor(m, o));
    float sum = 0.f;
#pragma unroll
    for (int u = 0; u < 8; ++u) { v[u] = __expf(v[u] - m); sum += v[u]; }
#pragma unroll
    for (int o = 4; o; o >>= 1) sum += __shfl_xor(sum, o);
    float inv = 1.f / sum;
    bf16x8 wv;
#pragma unroll
    for (int u = 0; u < 8; ++u) wv[u] = f2b(v[u] * inv);
    *(bf16x8*)((char*)wS + row * 128 + ((sg * 16) ^ ((row & 7) << 4))) = wv;
  }
  __syncthreads();

  float* sf = (float*)hS;  // [16][516]
  {
    bf16x8 af[2];
#pragma unroll
    for (int ks = 0; ks < 2; ++ks)
      af[ks] = *(const bf16x8*)((const char*)wS + llo * 128 + (((ks * 64 + lhi * 16)) ^ ((llo & 7) << 4)));
    const bf16_t* Tb = hlnT + (size_t)b * D_ * C_;
#pragma unroll
    for (int nt = 0; nt < 8; ++nt) {
      int dcol = wave * 128 + nt * 16 + llo;
      f32x4 acc = {};
#pragma unroll
      for (int ks = 0; ks < 2; ++ks) {
        bf16x8 bf = *(const bf16x8*)(Tb + (size_t)dcol * 64 + ks * 32 + lhi * 8);
        acc = __builtin_amdgcn_mfma_f32_16x16x32_bf16(af[ks], bf, acc, 0, 0, 0);
      }
#pragma unroll
      for (int r = 0; r < 4; ++r) sf[(lhi * 4 + r) * 516 + dcol] = acc[r];
    }
  }
  __syncthreads();

  {
    int lr = t >> 4, p = t & 15;
    float s = 0.f, q2 = 0.f;
#pragma unroll 8
    for (int i = 0; i < 32; ++i) {
      float v = sf[lr * 516 + p + 16 * i];
      s += v;
      q2 += v * v;
    }
#pragma unroll
    for (int o = 8; o; o >>= 1) { s += __shfl_xor(s, o); q2 += __shfl_xor(q2, o); }
    if (p == 0) {
      float mu = s * (1.0f / D_);
      mur[lr] = mu;
      rsr[lr] = rsqrtf(q2 * (1.0f / D_) - mu * mu + 1e-5f);
    }
  }
  __syncthreads();

  int d = 2 * t;
  float lwx = lnw[d], lwy = lnw[d + 1], lbx = lnbv[d], lby = lnbv[d + 1];
#pragma unroll 4
  for (int r = 0; r < 16; ++r) {
    float2 xy = *(const float2*)(&sf[r * 516 + d]);
    size_t go = ((size_t)b * C_ + q * 16 + r) * 512 + d;
    float mu = mur[r], rs = rsr[r];
    if constexpr (MODE == 0) {
      *(float2*)(hl1f + go) = xy;
      bf16x2 hb;
      hb.x = f2b(xy.x);
      hb.y = f2b(xy.y);
      *(bf16x2*)(hl1b + go) = hb;
    }
    bf16x2 lb2;
    lb2.x = f2b((xy.x - mu) * rs * lwx + lbx);
    lb2.y = f2b((xy.y - mu) * rs * lwy + lby);
    *(bf16x2*)(lnout + go) = lb2;
  }
}

// ---- fused layer2 head: per (b,c): h2a#1 for the 16 rows {j*64+c} (att1 bf16 out),
//      LN21 in-register, dot with G, 17-way softmax, u = sum p_j*attln_j, R = p_self*hl1 ----
__global__ __launch_bounds__(256) void k_l2head(const float* __restrict__ att,
                                                const bf16_t* __restrict__ hW,
                                                const float* __restrict__ hl1f,
                                                const bf16_t* __restrict__ G,
                                                const float* __restrict__ lw,
                                                const float* __restrict__ lb,
                                                bf16_t* __restrict__ att1b,
                                                bf16_t* __restrict__ u_out,
                                                bf16_t* __restrict__ R_out) {
  int blk = blockIdx.x;  // b*64 + c
  int b = blk >> 6, c = blk & 63;
  int t = threadIdx.x;
  int w = t >> 6, lane = t & 63;
  int d0 = lane * 8;
  __shared__ bf16_t lnS[16][512];
  __shared__ float hrow[512];
  __shared__ float wts[32];
  __shared__ float red[4];

  {  // stage hl1 row + self-dot
    int d = 2 * t;
    float2 h2 = *(const float2*)(hl1f + (size_t)blk * 512 + d);
    hrow[d] = h2.x;
    hrow[d + 1] = h2.y;
    float sd = h2.x * h2.x + h2.y * h2.y;
#pragma unroll
    for (int o = 32; o; o >>= 1) sd += __shfl_xor(sd, o);
    if (lane == 0) red[w] = sd;
  }
  // wave-private constants (same d0 for all of this wave's rows)
  bf16x8 wb = *(const bf16x8*)(hW + (size_t)blk * 512 + d0);
  bf16x8 gb = *(const bf16x8*)(G + (size_t)blk * 512 + d0);
  float wv[8], gv[8];
#pragma unroll
  for (int u = 0; u < 8; ++u) { wv[u] = b2f(wb[u]); gv[u] = b2f(gb[u]); }
  float4 w1 = *(const float4*)(lw + d0);
  float4 w2 = *(const float4*)(lw + d0 + 4);
  float4 b1 = *(const float4*)(lb + d0);
  float4 b2 = *(const float4*)(lb + d0 + 4);
  float lwv[8] = {w1.x, w1.y, w1.z, w1.w, w2.x, w2.y, w2.z, w2.w};
  float lbv[8] = {b1.x, b1.y, b1.z, b1.w, b2.x, b2.y, b2.z, b2.w};

  // hoisted loads: all 4 rows in flight before the reduce chains
  float av4[4][8];
#pragma unroll
  for (int i = 0; i < 4; ++i) {
    int j = w * 4 + i;
    const float* ar = att + ((size_t)b * A_ + j * 64 + c) * 512 + d0;
    float4 a1 = *(const float4*)ar;
    float4 a2 = *(const float4*)(ar + 4);
    av4[i][0] = a1.x; av4[i][1] = a1.y; av4[i][2] = a1.z; av4[i][3] = a1.w;
    av4[i][4] = a2.x; av4[i][5] = a2.y; av4[i][6] = a2.z; av4[i][7] = a2.w;
  }

#pragma unroll
  for (int i = 0; i < 4; ++i) {
    int j = w * 4 + i;
    size_t row = (size_t)b * A_ + j * 64 + c;
    float d1 = 0.f, d2 = 0.f;
#pragma unroll
    for (int u = 0; u < 8; ++u) { d1 += av4[i][u] * wv[u]; d2 += av4[i][u] * av4[i][u]; }
#pragma unroll
    for (int o = 32; o; o >>= 1) { d1 += __shfl_xor(d1, o); d2 += __shfl_xor(d2, o); }
    float s1 = d1 * INV_SD, s2 = d2 * INV_SD;
    float m = fmaxf(s1, s2);
    float e1 = __expf(s1 - m), e2 = __expf(s2 - m);
    float inv = 1.f / (e1 + e2);
    float alpha = e1 * inv, beta = e2 * inv;
    float o8[8], s = 0.f, q = 0.f;
    bf16x8 ob;
#pragma unroll
    for (int u = 0; u < 8; ++u) {
      o8[u] = alpha * wv[u] + beta * av4[i][u];
      s += o8[u];
      q += o8[u] * o8[u];
      ob[u] = f2b(o8[u]);
    }
    *(bf16x8*)(att1b + row * 512 + d0) = ob;
#pragma unroll
    for (int o = 32; o; o >>= 1) { s += __shfl_xor(s, o); q += __shfl_xor(q, o); }
    float mu = s * (1.0f / D_);
    float rs = rsqrtf(q * (1.0f / D_) - mu * mu + 1e-5f);
    float dot = 0.f;
    bf16x8 lnv;
#pragma unroll
    for (int u = 0; u < 8; ++u) {
      float v = (o8[u] - mu) * rs * lwv[u] + lbv[u];
      lnv[u] = f2b(v);
      dot += v * gv[u];
    }
    *(bf16x8*)(&lnS[j][d0]) = lnv;
#pragma unroll
    for (int o = 32; o; o >>= 1) dot += __shfl_xor(dot, o);
    if (lane == 0) wts[j] = dot * INV_SD;
  }
  __syncthreads();
  if (t == 0) wts[16] = ((red[0] + red[1]) + (red[2] + red[3])) * INV_SD;
  __syncthreads();
  if (t < 64) {
    float val = (t < 17) ? wts[t] : -3.0e38f;
    float m = val;
#pragma unroll
    for (int o = 32; o; o >>= 1) m = fmaxf(m, __shfl_xor(m, o));
    float e = (t < 17) ? __expf(val - m) : 0.f;
    float ssum = e;
#pragma unroll
    for (int o = 32; o; o >>= 1) ssum += __shfl_xor(ssum, o);
    if (t < 17) wts[t] = e / ssum;
  }
  __syncthreads();
  int d = 2 * t;
  float ux = 0.f, uy = 0.f;
#pragma unroll 4
  for (int jj = 0; jj < 16; ++jj) {
    bf16x2 l2 = *(const bf16x2*)(&lnS[jj][d]);
    ux += wts[jj] * b2f(l2.x);
    uy += wts[jj] * b2f(l2.y);
  }
  bf16x2 uo, ro;
  uo.x = f2b(ux);
  uo.y = f2b(uy);
  *(bf16x2*)(u_out + (size_t)blk * 512 + d) = uo;
  float w16 = wts[16];
  ro.x = f2b(w16 * hrow[d]);
  ro.y = f2b(w16 * hrow[d + 1]);
  *(bf16x2*)(R_out + (size_t)blk * 512 + d) = ro;
}

// ---- h2a #2 (final): att1 bf16 in, out f32 ----
__global__ __launch_bounds__(256) void k_h2a_out(const bf16_t* __restrict__ att,
                                                 const bf16_t* __restrict__ hW,
                                                 float* __restrict__ outp) {
  int t = threadIdx.x;
  int row = blockIdx.x * 4 + (t >> 6);
  int lane = t & 63;
  int b = row >> 10, a = row & 1023;
  int c = a & 63;
  int d0 = lane * 8;
  bf16x8 ab = *(const bf16x8*)(att + (size_t)row * D_ + d0);
  bf16x8 wb = *(const bf16x8*)(hW + (size_t)(b * 64 + c) * D_ + d0);
  float av[8], w[8];
#pragma unroll
  for (int u = 0; u < 8; ++u) { av[u] = b2f(ab[u]); w[u] = b2f(wb[u]); }
  float d1 = 0.f, d2 = 0.f;
#pragma unroll
  for (int u = 0; u < 8; ++u) { d1 += av[u] * w[u]; d2 += av[u] * av[u]; }
#pragma unroll
  for (int o = 32; o; o >>= 1) { d1 += __shfl_xor(d1, o); d2 += __shfl_xor(d2, o); }
  float s1 = d1 * INV_SD, s2 = d2 * INV_SD;
  float m = fmaxf(s1, s2);
  float e1 = __expf(s1 - m), e2 = __expf(s2 - m);
  float inv = 1.f / (e1 + e2);
  float alpha = e1 * inv, beta = e2 * inv;
  float4 o1, o2;
  o1.x = alpha * w[0] + beta * av[0]; o1.y = alpha * w[1] + beta * av[1];
  o1.z = alpha * w[2] + beta * av[2]; o1.w = alpha * w[3] + beta * av[3];
  o2.x = alpha * w[4] + beta * av[4]; o2.y = alpha * w[5] + beta * av[5];
  o2.z = alpha * w[6] + beta * av[6]; o2.w = alpha * w[7] + beta * av[7];
  float* orow = outp + (size_t)row * D_ + d0;
  *(float4*)orow = o1;
  *(float4*)(orow + 4) = o2;
}

extern "C" void kernel_launch(void* const* d_in, const int* in_sizes, int n_in,
                              void* d_out, int out_size, void* d_ws, size_t ws_size,
                              hipStream_t stream) {
  const float* att_vf = (const float*)d_in[0];
  const float* W1_h2h = (const float*)d_in[4];
  const float* W1_h2a = (const float*)d_in[5];
  const float* ln11w = (const float*)d_in[6];
  const float* ln11b = (const float*)d_in[7];
  const float* ln12w = (const float*)d_in[8];
  const float* ln12b = (const float*)d_in[9];
  const float* ln13w = (const float*)d_in[10];
  const float* ln13b = (const float*)d_in[11];
  const float* W2_a2h = (const float*)d_in[12];
  const float* W2_h2h = (const float*)d_in[13];
  const float* W2_h2a = (const float*)d_in[14];
  const float* ln21w = (const float*)d_in[15];
  const float* ln21b = (const float*)d_in[16];
  const float* ln22w = (const float*)d_in[17];
  const float* ln22b = (const float*)d_in[18];
  const float* ln23w = (const float*)d_in[19];
  const float* ln23b = (const float*)d_in[20];
  float* out = (float*)d_out;

  float* ws = (float*)d_ws;
  const size_t SM = (size_t)B_ * C_ * D_;  // 2097152 elems
  float* hl1f = ws;                                   // f32 [B*C*D]
  bf16_t* A1b = (bf16_t*)(hl1f + SM);                 // hln bf16
  bf16_t* A1t = (bf16_t*)((float*)A1b + SM / 2);      // hlnT bf16
  bf16_t* A2b = (bf16_t*)((float*)A1t + SM / 2);      // gemm out bf16
  bf16_t* hl1b = (bf16_t*)((float*)A2b + SM / 2);     // hl1 bf16
  bf16_t* u_b = (bf16_t*)((float*)hl1b + SM / 2);     // u bf16
  bf16_t* R_b = (bf16_t*)((float*)u_b + SM / 2);      // R bf16
  bf16_t* Gb = (bf16_t*)((float*)R_b + SM / 2);       // G bf16
  bf16_t* Wt0 = (bf16_t*)((float*)Gb + SM / 2);       // 6 weight slots
  const size_t WTE = (size_t)512 * 512;               // elems per slot
  bf16_t* att1b = Wt0 + 6 * WTE;                      // B*A*D bf16

  dim3 blk(256);
  // prep: hl0 (4096 blocks) + weight transpose/convert (384 blocks)
  k_prep<<<B_ * C_ + 384, blk, 0, stream>>>(att_vf, ln11w, ln11b, ln12w, ln12b, A1b,
                                            W1_h2h, W1_h2a, W2_a2h, W2_h2h, W2_h2a, Wt0);
  // hide1 GEMM (1024 tiles) + appended hln transpose blocks (512)
  k_gemm32<false><<<1536, blk, 0, stream>>>(A1b, Wt0 + 0 * WTE, A2b,
                                            A1b, Wt0 + 0 * WTE, A2b, nullptr, 1024, 1024,
                                            A1b, A1t);
  k_h2h<0><<<dim3(4, B_), blk, 0, stream>>>(A2b, A1t, ln13w, ln13b, hl1f, hl1b, A1b);  // hl1 + ln13
  // merged: hW1 = ln13 @ W1_h2a^T  AND  G = hl1 @ W2_a2h^T
  k_gemm32<false><<<2048, blk, 0, stream>>>(A1b, Wt0 + 1 * WTE, A2b,
                                            hl1b, Wt0 + 5 * WTE, Gb, nullptr, 1024, 2048,
                                            nullptr, nullptr);
  // fused layer2 head: att1 + LN21 + scores + softmax17 + u/R
  k_l2head<<<B_ * C_, blk, 0, stream>>>(att_vf, A2b, hl1f, Gb, ln21w, ln21b, att1b, u_b, R_b);
  k_gemm32<true><<<1024, blk, 0, stream>>>(u_b, Wt0 + 2 * WTE, A2b,
                                           u_b, Wt0 + 2 * WTE, A2b, R_b, 1024, 1024,
                                           nullptr, nullptr);  // hl2 = u@W + R
  k_ln_tr<<<B_, blk, 0, stream>>>(A2b, ln22w, ln22b, A1b, A1t);  // ln22 + transpose
  // h2h #2
  k_gemm32<false><<<1024, blk, 0, stream>>>(A1b, Wt0 + 3 * WTE, A2b,
                                            A1b, Wt0 + 3 * WTE, A2b, nullptr, 1024, 1024,
                                            nullptr, nullptr);  // hide2
  k_h2h<1><<<dim3(4, B_), blk, 0, stream>>>(A2b, A1t, ln23w, ln23b, nullptr, nullptr, A1b);  // ln23
  k_gemm32<false><<<1024, blk, 0, stream>>>(A1b, Wt0 + 4 * WTE, A2b,
                                            A1b, Wt0 + 4 * WTE, A2b, nullptr, 1024, 1024,
                                            nullptr, nullptr);  // hW2
  k_h2a_out<<<(B_ * A_) / 4, blk, 0, stream>>>(att1b, A2b, out);
}

// Round 13
// 181.728 us; speedup vs baseline: 1.0155x; 1.0155x over previous
//
#include <hip/hip_runtime.h>

#define B_ 64
#define A_ 1024
#define C_ 64
#define D_ 512
#define INV_SD 0.044194173824159216f

typedef __bf16 bf16_t;
typedef __bf16 bf16x8 __attribute__((ext_vector_type(8)));
typedef __bf16 bf16x2 __attribute__((ext_vector_type(2)));
typedef float f32x4 __attribute__((ext_vector_type(4)));

static __device__ __forceinline__ bf16_t f2b(float x) { return (bf16_t)x; }
static __device__ __forceinline__ float b2f(bf16_t x) { return (float)x; }

// async global->LDS, 16B per lane; LDS dest = wave-uniform base + lane*16 (linear)
static __device__ __forceinline__ void gl_lds16(const void* g, void* l) {
  __builtin_amdgcn_global_load_lds(
      (const __attribute__((address_space(1))) unsigned int*)g,
      (__attribute__((address_space(3))) unsigned int*)l, 16, 0, 0);
}

// ---- merged prep: blocks [0, B*C) do hl0 (LN11+avg+LN12 -> hln bf16);
//      blocks [B*C, B*C+384) do weight transpose/convert (6 slots) ----
__global__ __launch_bounds__(256) void k_prep(const float* __restrict__ att,
                                              const float* __restrict__ lw1,
                                              const float* __restrict__ lb1,
                                              const float* __restrict__ lw2,
                                              const float* __restrict__ lb2,
                                              bf16_t* __restrict__ hlnb,
                                              const float* __restrict__ W0,
                                              const float* __restrict__ W1,
                                              const float* __restrict__ W2,
                                              const float* __restrict__ W3,
                                              const float* __restrict__ W4,
                                              bf16_t* __restrict__ WtBase) {
  __shared__ float shm[64 * 65];  // 16.6 KB, aliased by both paths
  __shared__ float reds[8];
  int bid = blockIdx.x;
  int t = threadIdx.x;
  if (bid < B_ * C_) {
    int b = bid >> 6, c = bid & 63;
    int w = t >> 6, lane = t & 63;
    float (*part)[512] = (float(*)[512])shm;
    float vv[4][8];
#pragma unroll
    for (int i = 0; i < 4; ++i) {  // hoisted loads: 4 rows in flight
      int jj = w * 4 + i;
      const float* xr = att + ((size_t)b * A_ + jj * 64 + c) * D_ + lane * 8;
      float4 v1 = *(const float4*)xr;
      float4 v2 = *(const float4*)(xr + 4);
      vv[i][0] = v1.x; vv[i][1] = v1.y; vv[i][2] = v1.z; vv[i][3] = v1.w;
      vv[i][4] = v2.x; vv[i][5] = v2.y; vv[i][6] = v2.z; vv[i][7] = v2.w;
    }
    float ps[8] = {0.f, 0.f, 0.f, 0.f, 0.f, 0.f, 0.f, 0.f};
#pragma unroll
    for (int i = 0; i < 4; ++i) {
      float s = 0.f, q = 0.f;
#pragma unroll
      for (int u = 0; u < 8; ++u) { s += vv[i][u]; q += vv[i][u] * vv[i][u]; }
#pragma unroll
      for (int o = 32; o; o >>= 1) { s += __shfl_xor(s, o); q += __shfl_xor(q, o); }
      float mu = s * (1.0f / D_);
      float rs = rsqrtf(q * (1.0f / D_) - mu * mu + 1e-5f);
#pragma unroll
      for (int u = 0; u < 8; ++u) ps[u] += (vv[i][u] - mu) * rs;
    }
#pragma unroll
    for (int u = 0; u < 8; ++u) part[w][lane * 8 + u] = ps[u];
    __syncthreads();
    int d = 2 * t;
    float hx = ((part[0][d] + part[1][d]) + (part[2][d] + part[3][d])) * (1.f / 16.f) * lw1[d] + lb1[d];
    float hy = ((part[0][d + 1] + part[1][d + 1]) + (part[2][d + 1] + part[3][d + 1])) * (1.f / 16.f) * lw1[d + 1] + lb1[d + 1];
    float s = hx + hy, q = hx * hx + hy * hy;
#pragma unroll
    for (int o = 32; o; o >>= 1) { s += __shfl_xor(s, o); q += __shfl_xor(q, o); }
    int lane2 = t & 63, w2 = t >> 6;
    if (lane2 == 0) { reds[w2] = s; reds[4 + w2] = q; }
    __syncthreads();
    float S = (reds[0] + reds[1]) + (reds[2] + reds[3]);
    float Q = (reds[4] + reds[5]) + (reds[6] + reds[7]);
    float mu = S * (1.0f / D_);
    float rs = rsqrtf(Q * (1.0f / D_) - mu * mu + 1e-5f);
    bf16x2 ob;
    ob.x = f2b((hx - mu) * rs * lw2[d] + lb2[d]);
    ob.y = f2b((hy - mu) * rs * lw2[d + 1] + lb2[d + 1]);
    *(bf16x2*)(hlnb + (size_t)bid * D_ + d) = ob;
  } else {
    int idx = bid - B_ * C_;
    int z = idx >> 6;  // 0..5
    int rem = idx & 63;
    int k0 = (rem & 7) * 64, n0 = (rem >> 3) * 64;
    const float* Ws[5] = {W0, W1, W2, W3, W4};
    int r0 = t >> 6;
    int c = t & 63;
    if (z == 5) {  // raw bf16 convert of W2_a2h
      const float* W = Ws[2];
      bf16_t* Wt = WtBase + (size_t)5 * 512 * 512;
#pragma unroll 4
      for (int i = 0; i < 16; ++i) {
        int r = r0 * 16 + i;
        Wt[(size_t)(k0 + r) * 512 + n0 + c] = f2b(W[(size_t)(k0 + r) * 512 + n0 + c]);
      }
      return;
    }
    const float* W = Ws[z];
    bf16_t* Wt = WtBase + (size_t)z * 512 * 512;
    float (*tile)[65] = (float(*)[65])shm;
#pragma unroll 4
    for (int i = 0; i < 16; ++i) {
      int r = r0 * 16 + i;
      tile[r][c] = W[(size_t)(k0 + r) * 512 + n0 + c];
    }
    __syncthreads();
#pragma unroll 4
    for (int i = 0; i < 16; ++i) {
      int r = r0 * 16 + i;
      Wt[(size_t)(n0 + r) * 512 + k0 + c] = f2b(tile[c][r]);
    }
  }
}

// ---- merged: LN rows of one batch (bf16 in) -> row-major bf16 + transposed bf16 ----
__global__ __launch_bounds__(256) void k_ln_tr(const bf16_t* __restrict__ x,
                                               const float* __restrict__ lw,
                                               const float* __restrict__ lb,
                                               bf16_t* __restrict__ y,
                                               bf16_t* __restrict__ yt) {
  __shared__ bf16_t lnS[64][528];
  int b = blockIdx.x;
  int t = threadIdx.x;
  int wv = t >> 6, lane = t & 63;
  int d0 = lane * 8;
  float4 w1 = *(const float4*)(lw + d0);
  float4 w2 = *(const float4*)(lw + d0 + 4);
  float4 b1 = *(const float4*)(lb + d0);
  float4 b2 = *(const float4*)(lb + d0 + 4);
  float lwv[8] = {w1.x, w1.y, w1.z, w1.w, w2.x, w2.y, w2.z, w2.w};
  float lbv[8] = {b1.x, b1.y, b1.z, b1.w, b2.x, b2.y, b2.z, b2.w};
  const bf16_t* xb = x + (size_t)b * C_ * D_;
  bf16_t* yb = y + (size_t)b * C_ * D_;
#pragma unroll 4
  for (int i = 0; i < 16; ++i) {
    int r = wv * 16 + i;
    bf16x8 xv = *(const bf16x8*)(xb + (size_t)r * D_ + d0);
    float v[8], s = 0.f, q = 0.f;
#pragma unroll
    for (int u = 0; u < 8; ++u) { v[u] = b2f(xv[u]); s += v[u]; q += v[u] * v[u]; }
#pragma unroll
    for (int o = 32; o; o >>= 1) { s += __shfl_xor(s, o); q += __shfl_xor(q, o); }
    float mu = s * (1.0f / D_);
    float rs = rsqrtf(q * (1.0f / D_) - mu * mu + 1e-5f);
    bf16x8 ob;
#pragma unroll
    for (int u = 0; u < 8; ++u) ob[u] = f2b((v[u] - mu) * rs * lwv[u] + lbv[u]);
    *(bf16x8*)(yb + (size_t)r * D_ + d0) = ob;
    *(bf16x8*)(&lnS[r][d0]) = ob;
  }
  __syncthreads();
  bf16_t* tb = yt + (size_t)b * D_ * C_;
#pragma unroll
  for (int pass = 0; pass < 16; ++pass) {
    int d = pass * 32 + (t >> 3);
    int c0 = (t & 7) * 8;
    unsigned short tmp[8];
#pragma unroll
    for (int u = 0; u < 8; ++u) tmp[u] = *(const unsigned short*)&lnS[c0 + u][d];
    *(uint4*)(tb + (size_t)d * 64 + c0) = *(const uint4*)tmp;
  }
}

// ---- MFMA GEMM, 64x64 tiles, BK=64, dbuf LDS (8 phases, 32KB), dual-matrix merge +
//      optional appended transpose blocks (best-measured configuration, rounds 9/11) ----
template <bool BIAS>
__global__ __launch_bounds__(256, 4) void k_gemm64(const bf16_t* __restrict__ A0,
                                                   const bf16_t* __restrict__ W0,
                                                   bf16_t* __restrict__ C0,
                                                   const bf16_t* __restrict__ A1,
                                                   const bf16_t* __restrict__ W1,
                                                   bf16_t* __restrict__ C1,
                                                   const bf16_t* __restrict__ Rb,
                                                   int tiles_per, int ntiles,
                                                   const bf16_t* __restrict__ trS,
                                                   bf16_t* __restrict__ trD) {
  constexpr int ABYTES = 64 * 128;  // 64 rows x 64 bf16
  constexpr int BUF = 2 * ABYTES;   // A + B per buffer = 16 KB
  __shared__ char smem[2 * BUF];    // 32 KB; epilogue Cs + tr path alias

  int t = threadIdx.x;
  int bid = blockIdx.x;

  if (bid >= ntiles) {  // appended transpose block
    int idx = bid - ntiles;
    int n0 = idx & 7, b = idx >> 3;
    unsigned short(*sm)[72] = (unsigned short(*)[72])smem;
    const bf16_t* sb = trS + (size_t)b * C_ * D_;
    bf16_t* db = trD + (size_t)b * D_ * C_;
#pragma unroll
    for (int rep = 0; rep < 2; ++rep) {
      int f = t + rep * 256;
      int r = f >> 3, c8 = f & 7;
      uint4 v = *(const uint4*)(sb + (size_t)r * D_ + n0 * 64 + c8 * 8);
      unsigned int* p = (unsigned int*)&sm[r][c8 * 8];
      p[0] = v.x; p[1] = v.y; p[2] = v.z; p[3] = v.w;
    }
    __syncthreads();
#pragma unroll
    for (int rep = 0; rep < 2; ++rep) {
      int f = t + rep * 256;
      int nr = f >> 3, c8 = f & 7;
      unsigned short tmp[8];
#pragma unroll
      for (int u = 0; u < 8; ++u) tmp[u] = sm[c8 * 8 + u][nr];
      *(uint4*)(db + (size_t)(n0 * 64 + nr) * 64 + c8 * 8) = *(const uint4*)tmp;
    }
    return;
  }

  int lane = t & 63, wave = t >> 6;
  int wr = wave >> 1, wc = wave & 1;
  int lhi = lane >> 4, llo = lane & 15;

  int tile = (bid & 7) * (ntiles >> 3) + (bid >> 3);
  int sel = (tile >= tiles_per) ? 1 : 0;
  int tidx = tile - sel * tiles_per;
  int bm = tidx >> 3, bn = tidx & 7;

  const bf16_t* Ab = (sel ? A1 : A0) + (size_t)bm * 64 * 512;
  const bf16_t* Wb = (sel ? W1 : W0) + (size_t)bn * 64 * 512;
  bf16_t* Cmat = sel ? C1 : C0;

  int l3 = lane >> 3;
  int srcOff = ((lane & 7) ^ l3) * 8;  // pre-swizzled source (rule 21)

  auto stage = [&](int k0, int bi) {
    char* As = smem + bi * BUF;
    char* Bs = As + ABYTES;
#pragma unroll
    for (int i = 0; i < 2; ++i) {
      int r0 = wave * 16 + i * 8;
      gl_lds16(Ab + (size_t)(r0 + l3) * 512 + k0 + srcOff, As + r0 * 128);
      gl_lds16(Wb + (size_t)(r0 + l3) * 512 + k0 + srcOff, Bs + r0 * 128);
    }
  };

  f32x4 acc[2][2] = {};
  stage(0, 0);
  __syncthreads();

  for (int it = 0; it < 8; ++it) {
    int cur = it & 1;
    if (it < 7) stage((it + 1) * 64, cur ^ 1);  // issue BEFORE compute
    const char* As = smem + cur * BUF;
    const char* Bs = As + ABYTES;
#pragma unroll
    for (int kk = 0; kk < 2; ++kk) {
      bf16x8 af[2], bfr[2];
      int bofs = kk * 64 + lhi * 16;
#pragma unroll
      for (int tr = 0; tr < 2; ++tr) {
        int row = wr * 32 + tr * 16 + llo;
        af[tr] = *(const bf16x8*)(As + row * 128 + (bofs ^ ((row & 7) << 4)));
      }
#pragma unroll
      for (int tc = 0; tc < 2; ++tc) {
        int col = wc * 32 + tc * 16 + llo;
        bfr[tc] = *(const bf16x8*)(Bs + col * 128 + (bofs ^ ((col & 7) << 4)));
      }
#pragma unroll
      for (int tr = 0; tr < 2; ++tr)
#pragma unroll
        for (int tc = 0; tc < 2; ++tc)
          acc[tr][tc] = __builtin_amdgcn_mfma_f32_16x16x32_bf16(af[tr], bfr[tc], acc[tr][tc], 0, 0, 0);
    }
    __syncthreads();
  }

  bf16_t(*Cs)[80] = (bf16_t(*)[80])smem;  // 64 x 80 bf16, row stride 160B
#pragma unroll
  for (int tr = 0; tr < 2; ++tr) {
    int row = wr * 32 + tr * 16 + lhi * 4;
#pragma unroll
    for (int r = 0; r < 4; ++r)
#pragma unroll
      for (int tc = 0; tc < 2; ++tc) {
        float v = acc[tr][tc][r];
        if constexpr (BIAS)
          v += b2f(Rb[(size_t)(bm * 64 + row + r) * 512 + bn * 64 + wc * 32 + tc * 16 + llo]);
        Cs[row + r][wc * 32 + tc * 16 + llo] = f2b(v);
      }
  }
  __syncthreads();
#pragma unroll
  for (int it = 0; it < 2; ++it) {
    int idx = t + it * 256;
    int row = idx >> 3, c8 = idx & 7;
    uint4 v = *(const uint4*)(&Cs[row][c8 * 8]);
    *(uint4*)(Cmat + (size_t)(bm * 64 + row) * 512 + bn * 64 + c8 * 8) = v;
  }
}

// ---- fused h2h: gram(MFMA) + softmax + PV(MFMA) + epilogue LN ----
// MODE 0: write hl1f (f32), hl1b (bf16), lnout=LN(hl1) bf16.  MODE 1: lnout only.
template <int MODE>
__global__ __launch_bounds__(256) void k_h2h(const bf16_t* __restrict__ hide,
                                             const bf16_t* __restrict__ hlnT,
                                             const float* __restrict__ lnw,
                                             const float* __restrict__ lnbv,
                                             float* __restrict__ hl1f,
                                             bf16_t* __restrict__ hl1b,
                                             bf16_t* __restrict__ lnout) {
  __shared__ bf16_t hS[8 * 64 * 64];  // 64KB; reused as f32 sf[16][516] in epilogue
  __shared__ float sS[16][68];
  __shared__ bf16_t wS[16 * 64];
  __shared__ float mur[16], rsr[16];

  int q = blockIdx.x;
  int b = blockIdx.y;
  int t = threadIdx.x;
  int lane = t & 63, wave = t >> 6;
  int lhi = lane >> 4, llo = lane & 15;

  const bf16_t* Hb = hide + (size_t)b * C_ * D_;
#pragma unroll
  for (int rep = 0; rep < 16; ++rep) {
    int f = t + rep * 256;
    int row = f >> 6, c16 = f & 63;
    int kc = c16 >> 3, ci = c16 & 7;
    uint4 v = *(const uint4*)(Hb + (size_t)row * 512 + c16 * 8);
    *(uint4*)((char*)hS + kc * 8192 + row * 128 + ((ci * 16) ^ ((row & 7) << 4))) = v;
  }
  __syncthreads();

  {
    f32x4 acc = {};
#pragma unroll
    for (int ks = 0; ks < 16; ++ks) {
      int kc = ks >> 1;
      int bofs = (ks & 1) * 64 + lhi * 16;
      int ra = q * 16 + llo;
      int rb = wave * 16 + llo;
      bf16x8 af = *(const bf16x8*)((const char*)hS + kc * 8192 + ra * 128 + (bofs ^ ((ra & 7) << 4)));
      bf16x8 bf = *(const bf16x8*)((const char*)hS + kc * 8192 + rb * 128 + (bofs ^ ((rb & 7) << 4)));
      acc = __builtin_amdgcn_mfma_f32_16x16x32_bf16(af, bf, acc, 0, 0, 0);
    }
#pragma unroll
    for (int r = 0; r < 4; ++r) sS[lhi * 4 + r][wave * 16 + llo] = acc[r] * INV_SD;
  }
  __syncthreads();

  if (t < 128) {
    int row = t >> 3, sg = t & 7;
    float v[8];
#pragma unroll
    for (int u = 0; u < 8; ++u) v[u] = sS[row][sg * 8 + u];
    float m = v[0];
#pragma unroll
    for (int u = 1; u < 8; ++u) m = fmaxf(m, v[u]);
#pragma unroll
    for (int o = 4; o; o >>= 1) m = fmaxf(m, __shfl_xor(m, o));
    float sum = 0.f;
#pragma unroll
    for (int u = 0; u < 8; ++u) { v[u] = __expf(v[u] - m); sum += v[u]; }
#pragma unroll
    for (int o = 4; o; o >>= 1) sum += __shfl_xor(sum, o);
    float inv = 1.f / sum;
    bf16x8 wv;
#pragma unroll
    for (int u = 0; u < 8; ++u) wv[u] = f2b(v[u] * inv);
    *(bf16x8*)((char*)wS + row * 128 + ((sg * 16) ^ ((row & 7) << 4))) = wv;
  }
  __syncthreads();

  float* sf = (float*)hS;  // [16][516]
  {
    bf16x8 af[2];
#pragma unroll
    for (int ks = 0; ks < 2; ++ks)
      af[ks] = *(const bf16x8*)((const char*)wS + llo * 128 + (((ks * 64 + lhi * 16)) ^ ((llo & 7) << 4)));
    const bf16_t* Tb = hlnT + (size_t)b * D_ * C_;
#pragma unroll
    for (int nt = 0; nt < 8; ++nt) {
      int dcol = wave * 128 + nt * 16 + llo;
      f32x4 acc = {};
#pragma unroll
      for (int ks = 0; ks < 2; ++ks) {
        bf16x8 bf = *(const bf16x8*)(Tb + (size_t)dcol * 64 + ks * 32 + lhi * 8);
        acc = __builtin_amdgcn_mfma_f32_16x16x32_bf16(af[ks], bf, acc, 0, 0, 0);
      }
#pragma unroll
      for (int r = 0; r < 4; ++r) sf[(lhi * 4 + r) * 516 + dcol] = acc[r];
    }
  }
  __syncthreads();

  {
    int lr = t >> 4, p = t & 15;
    float s = 0.f, q2 = 0.f;
#pragma unroll 8
    for (int i = 0; i < 32; ++i) {
      float v = sf[lr * 516 + p + 16 * i];
      s += v;
      q2 += v * v;
    }
#pragma unroll
    for (int o = 8; o; o >>= 1) { s += __shfl_xor(s, o); q2 += __shfl_xor(q2, o); }
    if (p == 0) {
      float mu = s * (1.0f / D_);
      mur[lr] = mu;
      rsr[lr] = rsqrtf(q2 * (1.0f / D_) - mu * mu + 1e-5f);
    }
  }
  __syncthreads();

  int d = 2 * t;
  float lwx = lnw[d], lwy = lnw[d + 1], lbx = lnbv[d], lby = lnbv[d + 1];
#pragma unroll 4
  for (int r = 0; r < 16; ++r) {
    float2 xy = *(const float2*)(&sf[r * 516 + d]);
    size_t go = ((size_t)b * C_ + q * 16 + r) * 512 + d;
    float mu = mur[r], rs = rsr[r];
    if constexpr (MODE == 0) {
      *(float2*)(hl1f + go) = xy;
      bf16x2 hb;
      hb.x = f2b(xy.x);
      hb.y = f2b(xy.y);
      *(bf16x2*)(hl1b + go) = hb;
    }
    bf16x2 lb2;
    lb2.x = f2b((xy.x - mu) * rs * lwx + lbx);
    lb2.y = f2b((xy.y - mu) * rs * lwy + lby);
    *(bf16x2*)(lnout + go) = lb2;
  }
}

// ---- fused layer2 head: per (b,c): h2a#1 for the 16 rows {j*64+c} (att1 bf16 out),
//      LN21 in-register, dot with G, 17-way softmax, u = sum p_j*attln_j, R = p_self*hl1 ----
__global__ __launch_bounds__(256) void k_l2head(const float* __restrict__ att,
                                                const bf16_t* __restrict__ hW,
                                                const float* __restrict__ hl1f,
                                                const bf16_t* __restrict__ G,
                                                const float* __restrict__ lw,
                                                const float* __restrict__ lb,
                                                bf16_t* __restrict__ att1b,
                                                bf16_t* __restrict__ u_out,
                                                bf16_t* __restrict__ R_out) {
  int blk = blockIdx.x;  // b*64 + c
  int b = blk >> 6, c = blk & 63;
  int t = threadIdx.x;
  int w = t >> 6, lane = t & 63;
  int d0 = lane * 8;
  __shared__ bf16_t lnS[16][512];
  __shared__ float hrow[512];
  __shared__ float wts[32];
  __shared__ float red[4];

  {  // stage hl1 row + self-dot
    int d = 2 * t;
    float2 h2 = *(const float2*)(hl1f + (size_t)blk * 512 + d);
    hrow[d] = h2.x;
    hrow[d + 1] = h2.y;
    float sd = h2.x * h2.x + h2.y * h2.y;
#pragma unroll
    for (int o = 32; o; o >>= 1) sd += __shfl_xor(sd, o);
    if (lane == 0) red[w] = sd;
  }
  // wave-private constants (same d0 for all of this wave's rows)
  bf16x8 wb = *(const bf16x8*)(hW + (size_t)blk * 512 + d0);
  bf16x8 gb = *(const bf16x8*)(G + (size_t)blk * 512 + d0);
  float wv[8], gv[8];
#pragma unroll
  for (int u = 0; u < 8; ++u) { wv[u] = b2f(wb[u]); gv[u] = b2f(gb[u]); }
  float4 w1 = *(const float4*)(lw + d0);
  float4 w2 = *(const float4*)(lw + d0 + 4);
  float4 b1 = *(const float4*)(lb + d0);
  float4 b2 = *(const float4*)(lb + d0 + 4);
  float lwv[8] = {w1.x, w1.y, w1.z, w1.w, w2.x, w2.y, w2.z, w2.w};
  float lbv[8] = {b1.x, b1.y, b1.z, b1.w, b2.x, b2.y, b2.z, b2.w};

  // hoisted loads: all 4 rows in flight before the reduce chains
  float av4[4][8];
#pragma unroll
  for (int i = 0; i < 4; ++i) {
    int j = w * 4 + i;
    const float* ar = att + ((size_t)b * A_ + j * 64 + c) * 512 + d0;
    float4 a1 = *(const float4*)ar;
    float4 a2 = *(const float4*)(ar + 4);
    av4[i][0] = a1.x; av4[i][1] = a1.y; av4[i][2] = a1.z; av4[i][3] = a1.w;
    av4[i][4] = a2.x; av4[i][5] = a2.y; av4[i][6] = a2.z; av4[i][7] = a2.w;
  }

#pragma unroll
  for (int i = 0; i < 4; ++i) {
    int j = w * 4 + i;
    size_t row = (size_t)b * A_ + j * 64 + c;
    float d1 = 0.f, d2 = 0.f;
#pragma unroll
    for (int u = 0; u < 8; ++u) { d1 += av4[i][u] * wv[u]; d2 += av4[i][u] * av4[i][u]; }
#pragma unroll
    for (int o = 32; o; o >>= 1) { d1 += __shfl_xor(d1, o); d2 += __shfl_xor(d2, o); }
    float s1 = d1 * INV_SD, s2 = d2 * INV_SD;
    float m = fmaxf(s1, s2);
    float e1 = __expf(s1 - m), e2 = __expf(s2 - m);
    float inv = 1.f / (e1 + e2);
    float alpha = e1 * inv, beta = e2 * inv;
    float o8[8], s = 0.f, q = 0.f;
    bf16x8 ob;
#pragma unroll
    for (int u = 0; u < 8; ++u) {
      o8[u] = alpha * wv[u] + beta * av4[i][u];
      s += o8[u];
      q += o8[u] * o8[u];
      ob[u] = f2b(o8[u]);
    }
    *(bf16x8*)(att1b + row * 512 + d0) = ob;
#pragma unroll
    for (int o = 32; o; o >>= 1) { s += __shfl_xor(s, o); q += __shfl_xor(q, o); }
    float mu = s * (1.0f / D_);
    float rs = rsqrtf(q * (1.0f / D_) - mu * mu + 1e-5f);
    float dot = 0.f;
    bf16x8 lnv;
#pragma unroll
    for (int u = 0; u < 8; ++u) {
      float v = (o8[u] - mu) * rs * lwv[u] + lbv[u];
      lnv[u] = f2b(v);
      dot += v * gv[u];
    }
    *(bf16x8*)(&lnS[j][d0]) = lnv;
#pragma unroll
    for (int o = 32; o; o >>= 1) dot += __shfl_xor(dot, o);
    if (lane == 0) wts[j] = dot * INV_SD;
  }
  __syncthreads();
  if (t == 0) wts[16] = ((red[0] + red[1]) + (red[2] + red[3])) * INV_SD;
  __syncthreads();
  if (t < 64) {
    float val = (t < 17) ? wts[t] : -3.0e38f;
    float m = val;
#pragma unroll
    for (int o = 32; o; o >>= 1) m = fmaxf(m, __shfl_xor(m, o));
    float e = (t < 17) ? __expf(val - m) : 0.f;
    float ssum = e;
#pragma unroll
    for (int o = 32; o; o >>= 1) ssum += __shfl_xor(ssum, o);
    if (t < 17) wts[t] = e / ssum;
  }
  __syncthreads();
  int d = 2 * t;
  float ux = 0.f, uy = 0.f;
#pragma unroll 4
  for (int jj = 0; jj < 16; ++jj) {
    bf16x2 l2 = *(const bf16x2*)(&lnS[jj][d]);
    ux += wts[jj] * b2f(l2.x);
    uy += wts[jj] * b2f(l2.y);
  }
  bf16x2 uo, ro;
  uo.x = f2b(ux);
  uo.y = f2b(uy);
  *(bf16x2*)(u_out + (size_t)blk * 512 + d) = uo;
  float w16 = wts[16];
  ro.x = f2b(w16 * hrow[d]);
  ro.y = f2b(w16 * hrow[d + 1]);
  *(bf16x2*)(R_out + (size_t)blk * 512 + d) = ro;
}

// ---- h2a #2 (final): att1 bf16 in, out f32 ----
__global__ __launch_bounds__(256) void k_h2a_out(const bf16_t* __restrict__ att,
                                                 const bf16_t* __restrict__ hW,
                                                 float* __restrict__ outp) {
  int t = threadIdx.x;
  int row = blockIdx.x * 4 + (t >> 6);
  int lane = t & 63;
  int b = row >> 10, a = row & 1023;
  int c = a & 63;
  int d0 = lane * 8;
  bf16x8 ab = *(const bf16x8*)(att + (size_t)row * D_ + d0);
  bf16x8 wb = *(const bf16x8*)(hW + (size_t)(b * 64 + c) * D_ + d0);
  float av[8], w[8];
#pragma unroll
  for (int u = 0; u < 8; ++u) { av[u] = b2f(ab[u]); w[u] = b2f(wb[u]); }
  float d1 = 0.f, d2 = 0.f;
#pragma unroll
  for (int u = 0; u < 8; ++u) { d1 += av[u] * w[u]; d2 += av[u] * av[u]; }
#pragma unroll
  for (int o = 32; o; o >>= 1) { d1 += __shfl_xor(d1, o); d2 += __shfl_xor(d2, o); }
  float s1 = d1 * INV_SD, s2 = d2 * INV_SD;
  float m = fmaxf(s1, s2);
  float e1 = __expf(s1 - m), e2 = __expf(s2 - m);
  float inv = 1.f / (e1 + e2);
  float alpha = e1 * inv, beta = e2 * inv;
  float4 o1, o2;
  o1.x = alpha * w[0] + beta * av[0]; o1.y = alpha * w[1] + beta * av[1];
  o1.z = alpha * w[2] + beta * av[2]; o1.w = alpha * w[3] + beta * av[3];
  o2.x = alpha * w[4] + beta * av[4]; o2.y = alpha * w[5] + beta * av[5];
  o2.z = alpha * w[6] + beta * av[6]; o2.w = alpha * w[7] + beta * av[7];
  float* orow = outp + (size_t)row * D_ + d0;
  *(float4*)orow = o1;
  *(float4*)(orow + 4) = o2;
}

extern "C" void kernel_launch(void* const* d_in, const int* in_sizes, int n_in,
                              void* d_out, int out_size, void* d_ws, size_t ws_size,
                              hipStream_t stream) {
  const float* att_vf = (const float*)d_in[0];
  const float* W1_h2h = (const float*)d_in[4];
  const float* W1_h2a = (const float*)d_in[5];
  const float* ln11w = (const float*)d_in[6];
  const float* ln11b = (const float*)d_in[7];
  const float* ln12w = (const float*)d_in[8];
  const float* ln12b = (const float*)d_in[9];
  const float* ln13w = (const float*)d_in[10];
  const float* ln13b = (const float*)d_in[11];
  const float* W2_a2h = (const float*)d_in[12];
  const float* W2_h2h = (const float*)d_in[13];
  const float* W2_h2a = (const float*)d_in[14];
  const float* ln21w = (const float*)d_in[15];
  const float* ln21b = (const float*)d_in[16];
  const float* ln22w = (const float*)d_in[17];
  const float* ln22b = (const float*)d_in[18];
  const float* ln23w = (const float*)d_in[19];
  const float* ln23b = (const float*)d_in[20];
  float* out = (float*)d_out;

  float* ws = (float*)d_ws;
  const size_t SM = (size_t)B_ * C_ * D_;  // 2097152 elems
  float* hl1f = ws;                                   // f32 [B*C*D]
  bf16_t* A1b = (bf16_t*)(hl1f + SM);                 // hln bf16
  bf16_t* A1t = (bf16_t*)((float*)A1b + SM / 2);      // hlnT bf16
  bf16_t* A2b = (bf16_t*)((float*)A1t + SM / 2);      // gemm out bf16
  bf16_t* hl1b = (bf16_t*)((float*)A2b + SM / 2);     // hl1 bf16
  bf16_t* u_b = (bf16_t*)((float*)hl1b + SM / 2);     // u bf16
  bf16_t* R_b = (bf16_t*)((float*)u_b + SM / 2);      // R bf16
  bf16_t* Gb = (bf16_t*)((float*)R_b + SM / 2);       // G bf16
  bf16_t* Wt0 = (bf16_t*)((float*)Gb + SM / 2);       // 6 weight slots
  const size_t WTE = (size_t)512 * 512;               // elems per slot
  bf16_t* att1b = Wt0 + 6 * WTE;                      // B*A*D bf16

  dim3 blk(256);
  // prep: hl0 (4096 blocks) + weight transpose/convert (384 blocks)
  k_prep<<<B_ * C_ + 384, blk, 0, stream>>>(att_vf, ln11w, ln11b, ln12w, ln12b, A1b,
                                            W1_h2h, W1_h2a, W2_a2h, W2_h2h, W2_h2a, Wt0);
  // hide1 GEMM (512 tiles) + appended hln transpose blocks (512)
  k_gemm64<false><<<1024, blk, 0, stream>>>(A1b, Wt0 + 0 * WTE, A2b,
                                            A1b, Wt0 + 0 * WTE, A2b, nullptr, 512, 512,
                                            A1b, A1t);
  k_h2h<0><<<dim3(4, B_), blk, 0, stream>>>(A2b, A1t, ln13w, ln13b, hl1f, hl1b, A1b);  // hl1 + ln13
  // merged: hW1 = ln13 @ W1_h2a^T  AND  G = hl1 @ W2_a2h^T
  k_gemm64<false><<<1024, blk, 0, stream>>>(A1b, Wt0 + 1 * WTE, A2b,
                                            hl1b, Wt0 + 5 * WTE, Gb, nullptr, 512, 1024,
                                            nullptr, nullptr);
  // fused layer2 head: att1 + LN21 + scores + softmax17 + u/R
  k_l2head<<<B_ * C_, blk, 0, stream>>>(att_vf, A2b, hl1f, Gb, ln21w, ln21b, att1b, u_b, R_b);
  k_gemm64<true><<<512, blk, 0, stream>>>(u_b, Wt0 + 2 * WTE, A2b,
                                          u_b, Wt0 + 2 * WTE, A2b, R_b, 512, 512,
                                          nullptr, nullptr);  // hl2 = u@W + R
  k_ln_tr<<<B_, blk, 0, stream>>>(A2b, ln22w, ln22b, A1b, A1t);  // ln22 + transpose
  // h2h #2
  k_gemm64<false><<<512, blk, 0, stream>>>(A1b, Wt0 + 3 * WTE, A2b,
                                           A1b, Wt0 + 3 * WTE, A2b, nullptr, 512, 512,
                                           nullptr, nullptr);  // hide2
  k_h2h<1><<<dim3(4, B_), blk, 0, stream>>>(A2b, A1t, ln23w, ln23b, nullptr, nullptr, A1b);  // ln23
  k_gemm64<false><<<512, blk, 0, stream>>>(A1b, Wt0 + 4 * WTE, A2b,
                                           A1b, Wt0 + 4 * WTE, A2b, nullptr, 512, 512,
                                           nullptr, nullptr);  // hW2
  k_h2a_out<<<(B_ * A_) / 4, blk, 0, stream>>>(att1b, A2b, out);
}